// Round 5
// baseline (532.159 us; speedup 1.0000x reference)
//
#include <hip/hip_runtime.h>
#include <stdint.h>

// ---------------------------------------------------------------------------
// GC_FFM fusion block on MI355X (gfx950), bf16 MFMA pipeline.
// N=2, C=256, RC=32, H=W=64, HW=4096.
// R5: NHWC activation layout for the back half -> LDS-free, barrier-free
//     GEMMs (both MFMA operands direct 16B global frags); attn v2 with
//     double-buffered PT (1 barrier/iter) and 128-c blocks; final GEMM
//     writes NCHW fp32 d_out via float4.
// ---------------------------------------------------------------------------

typedef __bf16 bf16_t;
typedef __bf16 bf16x8 __attribute__((ext_vector_type(8)));
typedef float f32x4 __attribute__((ext_vector_type(4)));

#define HW 4096
#define NB 2

__device__ inline f32x4 mfma_bf16(bf16x8 a, bf16x8 b, f32x4 c) {
    return __builtin_amdgcn_mfma_f32_16x16x32_bf16(a, b, c, 0, 0, 0);
}

__device__ inline bf16x8 sel8(bool ok, bf16x8 x) {
    union { bf16x8 b; uint32_t u[4]; } a;
    a.b = x;
#pragma unroll
    for (int i = 0; i < 4; i++) a.u[i] = ok ? a.u[i] : 0u;
    return a.b;
}

// ---------------------------------------------------------------------------
// Batched fp32 -> bf16 conversion (one launch for all weights + features).
// ---------------------------------------------------------------------------
#define MAXJOB 12
struct CvtJobs {
    const float* src[MAXJOB];
    bf16_t* dst[MAXJOB];
    int vend[MAXJOB];     // cumulative end, vec8 units
    int rowlen[MAXJOB];
    int rowstride[MAXJOB];
    int rowoff[MAXJOB];
};

__global__ __launch_bounds__(256) void convert_batch_k(CvtJobs J, int totalvec) {
    int gv = blockIdx.x * 256 + threadIdx.x;
    if (gv >= totalvec) return;
    int j = 0;
    while (gv >= J.vend[j]) j++;
    int vbase = (j == 0) ? 0 : J.vend[j - 1];
    int e = (gv - vbase) * 8;
    const float* s = J.src[j] + e;
    float4 f0 = *(const float4*)s;
    float4 f1 = *(const float4*)(s + 4);
    bf16x8 o;
    o[0] = (bf16_t)f0.x; o[1] = (bf16_t)f0.y; o[2] = (bf16_t)f0.z; o[3] = (bf16_t)f0.w;
    o[4] = (bf16_t)f1.x; o[5] = (bf16_t)f1.y; o[6] = (bf16_t)f1.z; o[7] = (bf16_t)f1.w;
    int di = e;
    if (J.rowlen[j])
        di = (e / J.rowlen[j]) * J.rowstride[j] + J.rowoff[j] + (e % J.rowlen[j]);
    *(bf16x8*)(J.dst[j] + di) = o;
}

// pack q/k biases into stacked [64] buffers + combined skip/fus3 bias
__global__ __launch_bounds__(256) void pack_bias_k(const float* qr, const float* kr,
                                                   const float* qd, const float* kd,
                                                   const float* sb, const float* fb,
                                                   float* BQK_R, float* BQK_D, float* BSUM) {
    int t = threadIdx.x;
    if (t < 32) {
        BQK_R[t] = qr[t]; BQK_R[32 + t] = kr[t];
        BQK_D[t] = qd[t]; BQK_D[32 + t] = kd[t];
    }
    BSUM[t] = sb[t] + fb[t];
}

// fus2_w [O=512][C=512][3][3] -> A'[o][ (dy*3+dx)*512 + c ]
__global__ __launch_bounds__(256) void reorder_fus2_k(const float* __restrict__ src,
                                                      bf16_t* __restrict__ dst) {
    int idx = blockIdx.x * 256 + threadIdx.x;
    if (idx >= 512 * 4608) return;
    int o = idx / 4608;
    int t = idx % 4608;
    int t9 = t / 512;
    int c  = t % 512;
    dst[idx] = (bf16_t)src[(size_t)o * 4608 + c * 9 + t9];
}

// ---------------------------------------------------------------------------
// Old-style LDS GEMM (R4-proven), kept ONLY for qk-proj (EPI 6) and V-proj
// (EPI 3), which need X^T staging and produce QKT / CHW V layouts.
// ---------------------------------------------------------------------------
template <int EPI>
__global__ __launch_bounds__(256) void gemm_k(const bf16_t* __restrict__ A,
                                              const bf16_t* __restrict__ A2,
                                              const bf16_t* __restrict__ B,
                                              const float* __restrict__ bias,
                                              const float* __restrict__ bias2,
                                              void* __restrict__ outp,
                                              const float* __restrict__ aux,
                                              int M, int K, size_t strideB, size_t strideO) {
    __shared__ bf16_t Bt[64][72];
    const int t = threadIdx.x;
    const int mb = blockIdx.x, jb = blockIdx.y, n = blockIdx.z;
    const int w = t >> 6, lane = t & 63, quad = lane >> 4, l16 = lane & 15;

    const bf16_t* Au = (n >= 2) ? A2 : A;
    const float* biasu = (n >= 2) ? bias2 : bias;

    const bf16_t* Bb = B + (size_t)n * strideB + jb * 64;
    const int srow = t >> 2;
    const int scol = (t & 3) << 4;

    f32x4 zero = {0.f, 0.f, 0.f, 0.f};
    f32x4 acc[4] = {zero, zero, zero, zero};

    const bf16_t* Arow = Au + (size_t)(mb * 64 + w * 16 + l16) * K + quad * 8;

    for (int k0 = 0; k0 < K; k0 += 64) {
        const bf16_t* src = Bb + (size_t)(k0 + srow) * HW + scol;
        bf16x8 v0 = *(const bf16x8*)src;
        bf16x8 v1 = *(const bf16x8*)(src + 8);
        __syncthreads();
#pragma unroll
        for (int e = 0; e < 8; e++) Bt[scol + e][srow] = v0[e];
#pragma unroll
        for (int e = 0; e < 8; e++) Bt[scol + 8 + e][srow] = v1[e];
        __syncthreads();

        bf16x8 a0 = *(const bf16x8*)(Arow + k0);
        bf16x8 a1 = *(const bf16x8*)(Arow + k0 + 32);
#pragma unroll
        for (int ns = 0; ns < 4; ns++) {
            bf16x8 b0 = *(const bf16x8*)&Bt[ns * 16 + l16][quad * 8];
            bf16x8 b1 = *(const bf16x8*)&Bt[ns * 16 + l16][32 + quad * 8];
            acc[ns] = mfma_bf16(a0, b0, acc[ns]);
            acc[ns] = mfma_bf16(a1, b1, acc[ns]);
        }
    }

    if (EPI == 6) {
        // transposed store: QKT[z][col][64] (M=64, mb=0)
#pragma unroll
        for (int ns = 0; ns < 4; ns++) {
            int col = jb * 64 + ns * 16 + l16;
            union { bf16_t h[4]; unsigned long long u; } pk;
#pragma unroll
            for (int rr = 0; rr < 4; rr++) {
                int m = w * 16 + quad * 4 + rr;
                pk.h[rr] = (bf16_t)(acc[ns][rr] + biasu[m]);
            }
            *(unsigned long long*)((bf16_t*)outp +
                ((size_t)n * HW + col) * 64 + w * 16 + quad * 4) = pk.u;
        }
    } else {
#pragma unroll
        for (int ns = 0; ns < 4; ns++) {
#pragma unroll
            for (int rr = 0; rr < 4; rr++) {
                int m = mb * 64 + w * 16 + quad * 4 + rr;
                int col = jb * 64 + ns * 16 + l16;
                float v = acc[ns][rr] + biasu[m];
                if (EPI == 3) v = v / aux[n * HW + col];
                ((bf16_t*)outp)[(size_t)n * strideO + (size_t)m * HW + col] = (bf16_t)v;
            }
        }
    }
}

// ---------------------------------------------------------------------------
// Attention pass A: Z[k][i] = sum_j exp( S[i,j] ), S from QKT slice k^2.
// Deterministic, LDS-free (R4-proven).
// ---------------------------------------------------------------------------
__global__ __launch_bounds__(256) void rowsum_k(const bf16_t* __restrict__ QKT,
                                                float* __restrict__ Z) {
    const int t = threadIdx.x, ib = blockIdx.x, k = blockIdx.y;
    const int w = t >> 6, lane = t & 63, quad = lane >> 4, l16 = lane & 15;
    const int qs = k ^ 2;
    const bf16_t* Q = QKT + (size_t)qs * HW * 64;

    bf16x8 a = *(const bf16x8*)(Q + (size_t)(ib * 64 + w * 16 + l16) * 64 + quad * 8);
    float zacc[4] = {0.f, 0.f, 0.f, 0.f};
    f32x4 zero = {0.f, 0.f, 0.f, 0.f};

    for (int jt = 0; jt < 64; jt++) {
#pragma unroll
        for (int ns = 0; ns < 4; ns++) {
            bf16x8 b = *(const bf16x8*)(Q + (size_t)(jt * 64 + ns * 16 + l16) * 64 + 32 + quad * 8);
            f32x4 s = mfma_bf16(a, b, zero);
#pragma unroll
            for (int rr = 0; rr < 4; rr++) zacc[rr] += __expf(s[rr]);
        }
    }

#pragma unroll
    for (int rr = 0; rr < 4; rr++) {
        for (int mask = 1; mask < 16; mask <<= 1)
            zacc[rr] += __shfl_xor(zacc[rr], mask, 64);
    }
    if (l16 == 0) {
#pragma unroll
        for (int rr = 0; rr < 4; rr++)
            Z[(size_t)k * HW + ib * 64 + w * 16 + quad * 4 + rr] = zacc[rr];
    }
}

// ---------------------------------------------------------------------------
// Attention pass B v2: D[j][c] = sum_i exp(S[i,j]) V'[c,i]; out NHWC CAT.
// A-op = PT (LDS, double-buffered, 1 barrier/iter); B-op = V [c][i] direct
// global frags. Block: 128 c (cb) x 64 j (jb), z in 0..3. Wave: 32 c strip
// for PV + 16 i strip for S. grid (2, 64, 4) = 512 blocks.
// ---------------------------------------------------------------------------
__global__ __launch_bounds__(256) void attn2_k(const bf16_t* __restrict__ QKT,
                                               const bf16_t* __restrict__ V,
                                               const float* __restrict__ rgb_feat,
                                               const float* __restrict__ chm_feat,
                                               bf16_t* __restrict__ CAT) {
    __shared__ bf16_t PT[2][64][72];  // [buf][j_local][i_local]
    const int t = threadIdx.x, cb = blockIdx.x, jb = blockIdx.y, z = blockIdx.z;
    const int w = t >> 6, lane = t & 63, quad = lane >> 4, l16 = lane & 15;
    const int qs = z ^ 2, n = z & 1;

    const bf16_t* Q = QKT + (size_t)qs * HW * 64;

    bf16x8 bS[4];  // K-side S fragments for this block's fixed j range
#pragma unroll
    for (int ns = 0; ns < 4; ns++)
        bS[ns] = *(const bf16x8*)(Q + (size_t)(jb * 64 + ns * 16 + l16) * 64 + 32 + quad * 8);

    f32x4 zero = {0.f, 0.f, 0.f, 0.f};
    f32x4 acc[2][4];
#pragma unroll
    for (int i = 0; i < 2; i++)
#pragma unroll
        for (int j = 0; j < 4; j++) acc[i][j] = zero;

    const bf16_t* Vb = V + ((size_t)z * 256 + cb * 128 + w * 32) * HW;

    for (int it = 0; it < 64; it++) {
        bf16x8 aS = *(const bf16x8*)(Q + (size_t)(it * 64 + w * 16 + l16) * 64 + quad * 8);
        bf16x8 bV[2][2];
#pragma unroll
        for (int ct = 0; ct < 2; ct++)
#pragma unroll
            for (int h = 0; h < 2; h++)
                bV[ct][h] = *(const bf16x8*)(Vb + (size_t)(ct * 16 + l16) * HW + it * 64 + h * 32 + quad * 8);

        const int p = it & 1;
        // safe: readers of PT[p] (iter it-2) all passed barrier(it-1)
#pragma unroll
        for (int ns = 0; ns < 4; ns++) {
            f32x4 s = mfma_bf16(aS, bS[ns], zero);
            union { bf16_t h[4]; unsigned long long u; } pk;
#pragma unroll
            for (int rr = 0; rr < 4; rr++) pk.h[rr] = (bf16_t)__expf(s[rr]);
            *(unsigned long long*)&PT[p][ns * 16 + l16][w * 16 + quad * 4] = pk.u;
        }
        __syncthreads();  // PT[p] ready

#pragma unroll
        for (int js = 0; js < 4; js++) {
            bf16x8 a0 = *(const bf16x8*)&PT[p][js * 16 + l16][quad * 8];
            bf16x8 a1 = *(const bf16x8*)&PT[p][js * 16 + l16][32 + quad * 8];
#pragma unroll
            for (int ct = 0; ct < 2; ct++) {
                acc[ct][js] = mfma_bf16(a0, bV[ct][0], acc[ct][js]);
                acc[ct][js] = mfma_bf16(a1, bV[ct][1], acc[ct][js]);
            }
        }
    }

    const float* feat = ((z < 2) ? rgb_feat : chm_feat) + (size_t)n * 256 * HW;
    const int cgo = (z < 2) ? 0 : 256;
#pragma unroll
    for (int ct = 0; ct < 2; ct++) {
#pragma unroll
        for (int js = 0; js < 4; js++) {
            int c = cb * 128 + w * 32 + ct * 16 + l16;
            int j0 = jb * 64 + js * 16 + quad * 4;
            float4 f = *(const float4*)(feat + (size_t)c * HW + j0);
            float fv[4] = {f.x, f.y, f.z, f.w};
#pragma unroll
            for (int rr = 0; rr < 4; rr++)
                CAT[((size_t)n * HW + j0 + rr) * 512 + cgo + c] =
                    (bf16_t)(acc[ct][js][rr] + fv[rr]);
        }
    }
}

// ---------------------------------------------------------------------------
// NHWC LDS-free GEMM: D[pix][m] = epi( sum_k X[pix][k] W[m][k] + bias[m] ).
// Block: 32 pixels x 256 m; wave w -> m [w*64, w*64+64). Both operands are
// direct contiguous 16B global fragments — no LDS, no barriers.
// EPI: 1 relu->bf16 NHWC (stride OS), 7 gate-fuse (sigmoid; reads CAT NHWC,
//      writes FY chans m & 256+m), 8 final (+bias -> fp32 NCHW float4 store)
// ---------------------------------------------------------------------------
template <int EPI>
__global__ __launch_bounds__(256) void ngemm_k(const bf16_t* __restrict__ X,
                                               const bf16_t* __restrict__ W,
                                               const float* __restrict__ bias,
                                               void* __restrict__ outp,
                                               const bf16_t* __restrict__ cat,
                                               int K, int XS, int OS) {
    const int t = threadIdx.x, pb = blockIdx.x, mh = blockIdx.y, n = blockIdx.z;
    const int w = t >> 6, lane = t & 63, quad = lane >> 4, l16 = lane & 15;
    const int mbase = mh * 256 + w * 64;

    const bf16_t* Xp = X + ((size_t)n * HW + pb * 32 + l16) * XS + quad * 8;

    f32x4 zero = {0.f, 0.f, 0.f, 0.f};
    f32x4 acc[4][2];
#pragma unroll
    for (int i = 0; i < 4; i++)
#pragma unroll
        for (int j = 0; j < 2; j++) acc[i][j] = zero;

    for (int k0 = 0; k0 < K; k0 += 64) {
        bf16x8 a[2][2];
#pragma unroll
        for (int ps = 0; ps < 2; ps++)
#pragma unroll
            for (int h = 0; h < 2; h++)
                a[ps][h] = *(const bf16x8*)(Xp + (size_t)(ps * 16) * XS + k0 + h * 32);
#pragma unroll
        for (int mt = 0; mt < 4; mt++) {
            const bf16_t* wp = W + (size_t)(mbase + mt * 16 + l16) * K + k0 + quad * 8;
            bf16x8 b0 = *(const bf16x8*)wp;
            bf16x8 b1 = *(const bf16x8*)(wp + 32);
#pragma unroll
            for (int ps = 0; ps < 2; ps++) {
                acc[mt][ps] = mfma_bf16(a[ps][0], b0, acc[mt][ps]);
                acc[mt][ps] = mfma_bf16(a[ps][1], b1, acc[mt][ps]);
            }
        }
    }

#pragma unroll
    for (int mt = 0; mt < 4; mt++) {
#pragma unroll
        for (int ps = 0; ps < 2; ps++) {
            int m = mbase + mt * 16 + l16;
            int pix0 = pb * 32 + ps * 16 + quad * 4;
            float bv = bias[m];
            if (EPI == 8) {
                float4 o;
                o.x = acc[mt][ps][0] + bv; o.y = acc[mt][ps][1] + bv;
                o.z = acc[mt][ps][2] + bv; o.w = acc[mt][ps][3] + bv;
                *(float4*)((float*)outp + (size_t)n * 256 * HW + (size_t)m * HW + pix0) = o;
            } else if (EPI == 7) {
#pragma unroll
                for (int rr = 0; rr < 4; rr++) {
                    int pix = pix0 + rr;
                    float g = 1.f / (1.f + __expf(-(acc[mt][ps][rr] + bv)));
                    size_t cb_ = ((size_t)n * HW + pix) * 512;
                    float br = (float)cat[cb_ + m];
                    float bd = (float)cat[cb_ + 256 + m];
                    size_t ob = ((size_t)n * HW + pix) * 1024;
                    ((bf16_t*)outp)[ob + m] = (bf16_t)(br * g + bd * (1.f - g));
                    ((bf16_t*)outp)[ob + 256 + m] = (bf16_t)(br * bd);
                }
            } else {
#pragma unroll
                for (int rr = 0; rr < 4; rr++) {
                    float v = acc[mt][ps][rr] + bv;
                    if (EPI == 1) v = v > 0.f ? v : 0.f;
                    ((bf16_t*)outp)[((size_t)n * HW + pix0 + rr) * OS + m] = (bf16_t)v;
                }
            }
        }
    }
}

// ---------------------------------------------------------------------------
// conv3x3, NHWC LDS-free implicit GEMM. Input Y1 NHWC [n][pix][512];
// output FY chans 512..1023 (stride 1024), relu+bias. Per tap: shifted
// a-frags with per-lane edge masking. grid (128, 2, 2).
// ---------------------------------------------------------------------------
__global__ __launch_bounds__(256) void conv3n_k(const bf16_t* __restrict__ W2,
                                                const bf16_t* __restrict__ Y1,
                                                const float* __restrict__ bias,
                                                bf16_t* __restrict__ FY) {
    const int t = threadIdx.x, pb = blockIdx.x, mh = blockIdx.y, n = blockIdx.z;
    const int w = t >> 6, lane = t & 63, quad = lane >> 4, l16 = lane & 15;
    const int y = pb >> 1, x0t = (pb & 1) * 32;
    const int mbase = mh * 256 + w * 64;

    const bf16_t* Yb = Y1 + (size_t)n * HW * 512;

    f32x4 zero = {0.f, 0.f, 0.f, 0.f};
    f32x4 acc[4][2];
#pragma unroll
    for (int i = 0; i < 4; i++)
#pragma unroll
        for (int j = 0; j < 2; j++) acc[i][j] = zero;

    for (int t9 = 0; t9 < 9; t9++) {
        const int dy = t9 / 3, dx = t9 % 3;
        const int yv = y + dy - 1;
        const bool yok = (unsigned)yv < 64u;
        int idx[2]; bool ok[2];
#pragma unroll
        for (int ps = 0; ps < 2; ps++) {
            int xv = x0t + ps * 16 + l16 + dx - 1;
            ok[ps] = yok && ((unsigned)xv < 64u);
            idx[ps] = ok[ps] ? (yv * 64 + xv) : 0;
        }
        const bf16_t* wb = W2 + t9 * 512 + quad * 8;
        for (int k0 = 0; k0 < 512; k0 += 64) {
            bf16x8 a[2][2];
#pragma unroll
            for (int ps = 0; ps < 2; ps++)
#pragma unroll
                for (int h = 0; h < 2; h++)
                    a[ps][h] = sel8(ok[ps],
                        *(const bf16x8*)(Yb + (size_t)idx[ps] * 512 + k0 + h * 32 + quad * 8));
#pragma unroll
            for (int mt = 0; mt < 4; mt++) {
                const bf16_t* wp = wb + (size_t)(mbase + mt * 16 + l16) * 4608 + k0;
                bf16x8 b0 = *(const bf16x8*)wp;
                bf16x8 b1 = *(const bf16x8*)(wp + 32);
#pragma unroll
                for (int ps = 0; ps < 2; ps++) {
                    acc[mt][ps] = mfma_bf16(a[ps][0], b0, acc[mt][ps]);
                    acc[mt][ps] = mfma_bf16(a[ps][1], b1, acc[mt][ps]);
                }
            }
        }
    }

#pragma unroll
    for (int mt = 0; mt < 4; mt++) {
#pragma unroll
        for (int ps = 0; ps < 2; ps++) {
            int m = mbase + mt * 16 + l16;
            int pix0 = pb * 32 + ps * 16 + quad * 4;
            float bv = bias[m];
#pragma unroll
            for (int rr = 0; rr < 4; rr++) {
                float v = acc[mt][ps][rr] + bv;
                v = v > 0.f ? v : 0.f;
                FY[((size_t)n * HW + pix0 + rr) * 1024 + 512 + m] = (bf16_t)v;
            }
        }
    }
}

// ---------------------------------------------------------------------------
extern "C" void kernel_launch(void* const* d_in, const int* in_sizes, int n_in,
                              void* d_out, int out_size, void* d_ws, size_t ws_size,
                              hipStream_t stream) {
    (void)in_sizes; (void)n_in; (void)out_size; (void)ws_size;

    const float* rgb_feat  = (const float*)d_in[0];
    const float* chm_feat  = (const float*)d_in[1];
    const float* rgb_q_w   = (const float*)d_in[2];
    const float* rgb_q_b   = (const float*)d_in[3];
    const float* rgb_k_w   = (const float*)d_in[4];
    const float* rgb_k_b   = (const float*)d_in[5];
    const float* rgb_v_w   = (const float*)d_in[6];
    const float* rgb_v_b   = (const float*)d_in[7];
    const float* depth_q_w = (const float*)d_in[8];
    const float* depth_q_b = (const float*)d_in[9];
    const float* depth_k_w = (const float*)d_in[10];
    const float* depth_k_b = (const float*)d_in[11];
    const float* depth_v_w = (const float*)d_in[12];
    const float* depth_v_b = (const float*)d_in[13];
    const float* gate_w    = (const float*)d_in[14];
    const float* gate_b    = (const float*)d_in[15];
    const float* fus1_w    = (const float*)d_in[16];
    const float* fus1_b    = (const float*)d_in[17];
    const float* fus2_w    = (const float*)d_in[18];
    const float* fus2_b    = (const float*)d_in[19];
    const float* fus3_w    = (const float*)d_in[20];
    const float* fus3_b    = (const float*)d_in[21];
    const float* skip_w    = (const float*)d_in[22];
    const float* skip_b    = (const float*)d_in[23];

    char* ws = (char*)d_ws;
    size_t off = 0;
    auto alloc = [&](size_t bytes) -> char* {
        char* p = ws + off;
        off += (bytes + 255) & ~(size_t)255;
        return p;
    };

    bf16_t* WQK_R = (bf16_t*)alloc(64 * 256 * 2);
    bf16_t* WQK_D = (bf16_t*)alloc(64 * 256 * 2);
    bf16_t* WV_R  = (bf16_t*)alloc(256 * 256 * 2);
    bf16_t* WV_D  = (bf16_t*)alloc(256 * 256 * 2);
    bf16_t* WGATE = (bf16_t*)alloc(256 * 512 * 2);
    bf16_t* WFUS1 = (bf16_t*)alloc(512 * 512 * 2);
    bf16_t* WFUS2 = (bf16_t*)alloc(512 * 4608 * 2);
    bf16_t* WCAT  = (bf16_t*)alloc(256 * 1024 * 2);      // [skip_w | fus3_w]
    float*  BQK_R = (float*)alloc(64 * 4);
    float*  BQK_D = (float*)alloc(64 * 4);
    float*  BSUM  = (float*)alloc(256 * 4);
    bf16_t* XB    = (bf16_t*)alloc((size_t)4 * 256 * HW * 2);    // NCHW bf16 [XR n0,n1; XC n0,n1]
    bf16_t* QKT   = (bf16_t*)alloc((size_t)4 * HW * 64 * 2);     // [z][pixel][64]
    float*  ZBUF  = (float*)alloc((size_t)4 * HW * 4);           // [k][HW]
    bf16_t* V4    = (bf16_t*)alloc((size_t)4 * 256 * HW * 2);    // CHW [z][c][pixel]
    bf16_t* CAT   = (bf16_t*)alloc((size_t)NB * HW * 512 * 2);   // NHWC [n][pix][512]
    bf16_t* FY    = (bf16_t*)alloc((size_t)NB * HW * 1024 * 2);  // NHWC [n][pix][1024] = [F;Y2]
    bf16_t* Y1    = (bf16_t*)alloc((size_t)NB * HW * 512 * 2);   // NHWC

    bf16_t* XR = XB;
    bf16_t* XC = XB + (size_t)2 * 256 * HW;

    // ---- prep: batched convert + bias pack ---------------------------------
    CvtJobs J;
    int cum = 0, nj = 0;
    auto addjob = [&](const float* s, bf16_t* d, int cnt, int rl, int rs, int ro) {
        J.src[nj] = s; J.dst[nj] = d; cum += cnt / 8; J.vend[nj] = cum;
        J.rowlen[nj] = rl; J.rowstride[nj] = rs; J.rowoff[nj] = ro; nj++;
    };
    addjob(rgb_feat, XR, NB * 256 * HW, 0, 0, 0);
    addjob(chm_feat, XC, NB * 256 * HW, 0, 0, 0);
    addjob(rgb_q_w, WQK_R, 32 * 256, 0, 0, 0);
    addjob(rgb_k_w, WQK_R + 32 * 256, 32 * 256, 0, 0, 0);
    addjob(depth_q_w, WQK_D, 32 * 256, 0, 0, 0);
    addjob(depth_k_w, WQK_D + 32 * 256, 32 * 256, 0, 0, 0);
    addjob(rgb_v_w, WV_R, 256 * 256, 0, 0, 0);
    addjob(depth_v_w, WV_D, 256 * 256, 0, 0, 0);
    addjob(gate_w, WGATE, 256 * 512, 0, 0, 0);
    addjob(fus1_w, WFUS1, 512 * 512, 0, 0, 0);
    addjob(skip_w, WCAT, 256 * 512, 512, 1024, 0);
    addjob(fus3_w, WCAT, 256 * 512, 512, 1024, 512);
    int totalvec = cum;
    convert_batch_k<<<dim3((totalvec + 255) / 256), 256, 0, stream>>>(J, totalvec);
    reorder_fus2_k<<<dim3(512 * 4608 / 256), 256, 0, stream>>>(fus2_w, WFUS2);
    pack_bias_k<<<dim3(1), 256, 0, stream>>>(rgb_q_b, rgb_k_b, depth_q_b, depth_k_b,
                                             skip_b, fus3_b, BQK_R, BQK_D, BSUM);

    // ---- q/k projections -> QKT[z][pixel][64] (z: 0,1 rgb; 2,3 depth) ------
    gemm_k<6><<<dim3(1, 64, 4), 256, 0, stream>>>(
        WQK_R, WQK_D, XB, BQK_R, BQK_D, QKT, nullptr, 64, 256, (size_t)256 * HW, 0);

    // ---- attention pass A: softmax denominators ----------------------------
    rowsum_k<<<dim3(64, 4), 256, 0, stream>>>(QKT, ZBUF);

    // ---- v projections, folded 1/Z scale -> V4 CHW -------------------------
    gemm_k<3><<<dim3(4, 64, 4), 256, 0, stream>>>(
        WV_R, WV_D, XB, rgb_v_b, depth_v_b, V4, ZBUF, 256, 256, (size_t)256 * HW, (size_t)256 * HW);

    // ---- attention pass B + residual -> CAT NHWC [br|bd] -------------------
    attn2_k<<<dim3(2, 64, 4), 256, 0, stream>>>(QKT, V4, rgb_feat, chm_feat, CAT);

    // ---- gate + gated fusion -> FY chans 0..511 ----------------------------
    ngemm_k<7><<<dim3(128, 1, NB), 256, 0, stream>>>(
        CAT, WGATE, gate_b, FY, CAT, 512, 512, 0);

    // ---- fus1 (relu) -> Y1 NHWC --------------------------------------------
    ngemm_k<1><<<dim3(128, 2, NB), 256, 0, stream>>>(
        FY, WFUS1, fus1_b, Y1, nullptr, 512, 1024, 512);

    // ---- fus2 conv3x3 (relu) -> FY chans 512..1023 -------------------------
    conv3n_k<<<dim3(128, 2, NB), 256, 0, stream>>>(WFUS2, Y1, fus2_b, FY);

    // ---- merged skip+fus3 -> d_out fp32 NCHW -------------------------------
    ngemm_k<8><<<dim3(128, 1, NB), 256, 0, stream>>>(
        FY, WCAT, BSUM, d_out, nullptr, 1024, 1024, 0);
}

// Round 6
// 402.171 us; speedup vs baseline: 1.3232x; 1.3232x over previous
//
#include <hip/hip_runtime.h>
#include <stdint.h>

// ---------------------------------------------------------------------------
// GC_FFM fusion block on MI355X (gfx950), bf16 MFMA pipeline.
// N=2, C=256, RC=32, H=W=64, HW=4096.
// R6: R4 pipeline (proven 413us) + attn v3 (double-buffered PT, 1 barrier/iter,
//     128-c blocks => 20 MFMA/iter/wave) + rowsum v2 (2 blocks/CU, j-split
//     across waves with LDS combine).
// R5 lesson: LDS-free GEMMs with large-stride operands = 16-line loads, no
// reuse, latency-bound at 7% MfmaUtil. Direct global frags only for small
// L2-hot pre-transposed tensors (QKT, V).
// ---------------------------------------------------------------------------

typedef __bf16 bf16_t;
typedef __bf16 bf16x8 __attribute__((ext_vector_type(8)));
typedef float f32x4 __attribute__((ext_vector_type(4)));

#define HW 4096
#define NB 2

__device__ inline f32x4 mfma_bf16(bf16x8 a, bf16x8 b, f32x4 c) {
    return __builtin_amdgcn_mfma_f32_16x16x32_bf16(a, b, c, 0, 0, 0);
}

// ---------------------------------------------------------------------------
// Batched fp32 -> bf16 conversion (one launch for all weights + features).
// ---------------------------------------------------------------------------
#define MAXJOB 12
struct CvtJobs {
    const float* src[MAXJOB];
    bf16_t* dst[MAXJOB];
    int vend[MAXJOB];     // cumulative end, vec8 units
    int rowlen[MAXJOB];
    int rowstride[MAXJOB];
    int rowoff[MAXJOB];
};

__global__ __launch_bounds__(256) void convert_batch_k(CvtJobs J, int totalvec) {
    int gv = blockIdx.x * 256 + threadIdx.x;
    if (gv >= totalvec) return;
    int j = 0;
    while (gv >= J.vend[j]) j++;
    int vbase = (j == 0) ? 0 : J.vend[j - 1];
    int e = (gv - vbase) * 8;
    const float* s = J.src[j] + e;
    float4 f0 = *(const float4*)s;
    float4 f1 = *(const float4*)(s + 4);
    bf16x8 o;
    o[0] = (bf16_t)f0.x; o[1] = (bf16_t)f0.y; o[2] = (bf16_t)f0.z; o[3] = (bf16_t)f0.w;
    o[4] = (bf16_t)f1.x; o[5] = (bf16_t)f1.y; o[6] = (bf16_t)f1.z; o[7] = (bf16_t)f1.w;
    int di = e;
    if (J.rowlen[j])
        di = (e / J.rowlen[j]) * J.rowstride[j] + J.rowoff[j] + (e % J.rowlen[j]);
    *(bf16x8*)(J.dst[j] + di) = o;
}

// pack q/k biases into stacked [64] buffers + combined skip/fus3 bias
__global__ __launch_bounds__(256) void pack_bias_k(const float* qr, const float* kr,
                                                   const float* qd, const float* kd,
                                                   const float* sb, const float* fb,
                                                   float* BQK_R, float* BQK_D, float* BSUM) {
    int t = threadIdx.x;
    if (t < 32) {
        BQK_R[t] = qr[t]; BQK_R[32 + t] = kr[t];
        BQK_D[t] = qd[t]; BQK_D[32 + t] = kd[t];
    }
    BSUM[t] = sb[t] + fb[t];
}

// fus2_w [O=512][C=512][3][3] -> A'[o][ (dy*3+dx)*512 + c ]
__global__ __launch_bounds__(256) void reorder_fus2_k(const float* __restrict__ src,
                                                      bf16_t* __restrict__ dst) {
    int idx = blockIdx.x * 256 + threadIdx.x;
    if (idx >= 512 * 4608) return;
    int o = idx / 4608;
    int t = idx % 4608;
    int t9 = t / 512;
    int c  = t % 512;
    dst[idx] = (bf16_t)src[(size_t)o * 4608 + c * 9 + t9];
}

// ---------------------------------------------------------------------------
// Generic bf16 GEMM (R4-proven): out = epi( A[z] . B[z] + bias ), dual-A.
// EPI: 0 none->fp32, 1 relu->bf16, 3 col-div by aux, 5 gate-fuse, 6 QKT store
// ---------------------------------------------------------------------------
template <int EPI, bool OUT_BF16>
__global__ __launch_bounds__(256) void gemm_k(const bf16_t* __restrict__ A,
                                              const bf16_t* __restrict__ A2,
                                              const bf16_t* __restrict__ B,
                                              const float* __restrict__ bias,
                                              const float* __restrict__ bias2,
                                              void* __restrict__ outp,
                                              const void* __restrict__ aux,
                                              int M, int K, size_t strideB, size_t strideO) {
    __shared__ bf16_t Bt[64][72];
    const int t = threadIdx.x;
    const int mb = blockIdx.x, jb = blockIdx.y, n = blockIdx.z;
    const int w = t >> 6, lane = t & 63, quad = lane >> 4, l16 = lane & 15;

    const bf16_t* Au = (n >= 2) ? A2 : A;
    const float* biasu = (n >= 2) ? bias2 : bias;

    const bf16_t* Bb = B + (size_t)n * strideB + jb * 64;
    const int srow = t >> 2;
    const int scol = (t & 3) << 4;

    f32x4 zero = {0.f, 0.f, 0.f, 0.f};
    f32x4 acc[4] = {zero, zero, zero, zero};

    const bf16_t* Arow = Au + (size_t)(mb * 64 + w * 16 + l16) * K + quad * 8;

    for (int k0 = 0; k0 < K; k0 += 64) {
        const bf16_t* src = Bb + (size_t)(k0 + srow) * HW + scol;
        bf16x8 v0 = *(const bf16x8*)src;
        bf16x8 v1 = *(const bf16x8*)(src + 8);
        __syncthreads();
#pragma unroll
        for (int e = 0; e < 8; e++) Bt[scol + e][srow] = v0[e];
#pragma unroll
        for (int e = 0; e < 8; e++) Bt[scol + 8 + e][srow] = v1[e];
        __syncthreads();

        bf16x8 a0 = *(const bf16x8*)(Arow + k0);
        bf16x8 a1 = *(const bf16x8*)(Arow + k0 + 32);
#pragma unroll
        for (int ns = 0; ns < 4; ns++) {
            bf16x8 b0 = *(const bf16x8*)&Bt[ns * 16 + l16][quad * 8];
            bf16x8 b1 = *(const bf16x8*)&Bt[ns * 16 + l16][32 + quad * 8];
            acc[ns] = mfma_bf16(a0, b0, acc[ns]);
            acc[ns] = mfma_bf16(a1, b1, acc[ns]);
        }
    }

    if (EPI == 6) {
        // transposed store: QKT[z][col][64] (M=64, mb=0)
#pragma unroll
        for (int ns = 0; ns < 4; ns++) {
            int col = jb * 64 + ns * 16 + l16;
            union { bf16_t h[4]; unsigned long long u; } pk;
#pragma unroll
            for (int rr = 0; rr < 4; rr++) {
                int m = w * 16 + quad * 4 + rr;
                pk.h[rr] = (bf16_t)(acc[ns][rr] + biasu[m]);
            }
            *(unsigned long long*)((bf16_t*)outp +
                ((size_t)n * HW + col) * 64 + w * 16 + quad * 4) = pk.u;
        }
    } else if (EPI == 5) {
        const bf16_t* catp = (const bf16_t*)aux;
        bf16_t* f = (bf16_t*)outp;
#pragma unroll
        for (int ns = 0; ns < 4; ns++) {
#pragma unroll
            for (int rr = 0; rr < 4; rr++) {
                int m = mb * 64 + w * 16 + quad * 4 + rr;
                int col = jb * 64 + ns * 16 + l16;
                float v = acc[ns][rr] + biasu[m];
                float g = 1.f / (1.f + __expf(-v));
                size_t base = (size_t)n * 512 * HW + (size_t)m * HW + col;
                float br = (float)catp[base];
                float bd = (float)catp[base + (size_t)256 * HW];
                size_t ob = (size_t)n * 1024 * HW + (size_t)m * HW + col;
                f[ob] = (bf16_t)(br * g + bd * (1.f - g));
                f[ob + (size_t)256 * HW] = (bf16_t)(br * bd);
            }
        }
    } else {
#pragma unroll
        for (int ns = 0; ns < 4; ns++) {
#pragma unroll
            for (int rr = 0; rr < 4; rr++) {
                int m = mb * 64 + w * 16 + quad * 4 + rr;
                int col = jb * 64 + ns * 16 + l16;
                float v = acc[ns][rr] + biasu[m];
                if (EPI == 1) v = v > 0.f ? v : 0.f;
                else if (EPI == 3) v = v / ((const float*)aux)[n * HW + col];
                size_t oi = (size_t)n * strideO + (size_t)m * HW + col;
                if (OUT_BF16) ((bf16_t*)outp)[oi] = (bf16_t)v;
                else ((float*)outp)[oi] = v;
            }
        }
    }
}

// ---------------------------------------------------------------------------
// conv3x3 implicit GEMM with haloed LDS tile (R2/R4-proven).
// ---------------------------------------------------------------------------
__global__ __launch_bounds__(256) void conv3_k(const bf16_t* __restrict__ A,
                                               const bf16_t* __restrict__ Bsrc,
                                               const float* __restrict__ bias,
                                               bf16_t* __restrict__ outp,
                                               size_t strideN) {
    __shared__ bf16_t kT[198][72];
    const int t = threadIdx.x;
    const int mb = blockIdx.x, y = blockIdx.y, n = blockIdx.z;
    const int w = t >> 6, lane = t & 63, quad = lane >> 4, l16 = lane & 15;

    if (t < 192) {
        int pr = t / 64, ct0 = t % 64;
        kT[pr * 66 + 0][ct0] = (bf16_t)0.f;
        kT[pr * 66 + 65][ct0] = (bf16_t)0.f;
    }

    f32x4 zero = {0.f, 0.f, 0.f, 0.f};
    f32x4 acc[2][4];
#pragma unroll
    for (int i = 0; i < 2; i++)
#pragma unroll
        for (int j = 0; j < 4; j++) acc[i][j] = zero;

    const bf16_t* Bb = Bsrc + (size_t)n * 512 * HW;
    const int ct = t >> 2, q4 = t & 3;

    const bf16_t* Arow0 = A + (size_t)(mb * 128 + w * 32 + l16) * 4608 + quad * 8;
    const bf16_t* Arow1 = Arow0 + (size_t)16 * 4608;

    for (int c0 = 0; c0 < 512; c0 += 64) {
        bf16x8 v[6];
#pragma unroll
        for (int i = 0; i < 6; i++) {
            int vid = q4 * 6 + i;
            int row = vid >> 3, xv = vid & 7;
            int yy = y + row - 1;
            if (yy >= 0 && yy < 64) {
                v[i] = *(const bf16x8*)(Bb + (size_t)(c0 + ct) * HW + yy * 64 + xv * 8);
            } else {
#pragma unroll
                for (int e = 0; e < 8; e++) v[i][e] = (bf16_t)0.f;
            }
        }
        __syncthreads();
#pragma unroll
        for (int i = 0; i < 6; i++) {
            int vid = q4 * 6 + i;
            int pbase = (vid >> 3) * 66 + (vid & 7) * 8 + 1;
#pragma unroll
            for (int e = 0; e < 8; e++) kT[pbase + e][ct] = v[i][e];
        }
        __syncthreads();

#pragma unroll
        for (int t9 = 0; t9 < 9; t9++) {
            const int dy = t9 / 3, dx = t9 % 3;
            const bf16_t* ap0 = Arow0 + t9 * 512 + c0;
            const bf16_t* ap1 = Arow1 + t9 * 512 + c0;
            bf16x8 a00 = *(const bf16x8*)(ap0);
            bf16x8 a01 = *(const bf16x8*)(ap0 + 32);
            bf16x8 a10 = *(const bf16x8*)(ap1);
            bf16x8 a11 = *(const bf16x8*)(ap1 + 32);
#pragma unroll
            for (int ns = 0; ns < 4; ns++) {
                int p = dy * 66 + ns * 16 + l16 + dx;
                bf16x8 b0 = *(const bf16x8*)&kT[p][quad * 8];
                bf16x8 b1 = *(const bf16x8*)&kT[p][32 + quad * 8];
                acc[0][ns] = mfma_bf16(a00, b0, acc[0][ns]);
                acc[0][ns] = mfma_bf16(a01, b1, acc[0][ns]);
                acc[1][ns] = mfma_bf16(a10, b0, acc[1][ns]);
                acc[1][ns] = mfma_bf16(a11, b1, acc[1][ns]);
            }
        }
    }

#pragma unroll
    for (int ms = 0; ms < 2; ms++) {
#pragma unroll
        for (int ns = 0; ns < 4; ns++) {
#pragma unroll
            for (int rr = 0; rr < 4; rr++) {
                int m = mb * 128 + w * 32 + ms * 16 + quad * 4 + rr;
                int x = ns * 16 + l16;
                float v = acc[ms][ns][rr] + bias[m];
                v = v > 0.f ? v : 0.f;
                outp[(size_t)n * strideN + (size_t)m * HW + y * 64 + x] = (bf16_t)v;
            }
        }
    }
}

// ---------------------------------------------------------------------------
// Attention pass A v2: Z[k][i] = sum_j exp(S[i,j]). 32 i-rows per block,
// waves split (i-strip x j-half), LDS combine. grid (128, 4) = 512 blocks.
// Deterministic: plain final store, no atomics.
// ---------------------------------------------------------------------------
__global__ __launch_bounds__(256) void rowsum_k(const bf16_t* __restrict__ QKT,
                                                float* __restrict__ Z) {
    __shared__ float Zp[2][32];
    const int t = threadIdx.x, ib = blockIdx.x, k = blockIdx.y;
    const int w = t >> 6, lane = t & 63, quad = lane >> 4, l16 = lane & 15;
    const int is = w & 1, jh = w >> 1;
    const int qs = k ^ 2;
    const bf16_t* Q = QKT + (size_t)qs * HW * 64;

    bf16x8 a = *(const bf16x8*)(Q + (size_t)(ib * 32 + is * 16 + l16) * 64 + quad * 8);
    float zacc[4] = {0.f, 0.f, 0.f, 0.f};
    f32x4 zero = {0.f, 0.f, 0.f, 0.f};

    for (int jt = jh * 32; jt < jh * 32 + 32; jt++) {
#pragma unroll
        for (int ns = 0; ns < 4; ns++) {
            bf16x8 b = *(const bf16x8*)(Q + (size_t)(jt * 64 + ns * 16 + l16) * 64 + 32 + quad * 8);
            f32x4 s = mfma_bf16(a, b, zero);
#pragma unroll
            for (int rr = 0; rr < 4; rr++) zacc[rr] += __expf(s[rr]);
        }
    }

#pragma unroll
    for (int rr = 0; rr < 4; rr++) {
        for (int mask = 1; mask < 16; mask <<= 1)
            zacc[rr] += __shfl_xor(zacc[rr], mask, 64);
    }
    if (l16 == 0) {
#pragma unroll
        for (int rr = 0; rr < 4; rr++)
            Zp[jh][is * 16 + quad * 4 + rr] = zacc[rr];
    }
    __syncthreads();
    if (t < 32)
        Z[(size_t)k * HW + ib * 32 + t] = Zp[0][t] + Zp[1][t];
}

// ---------------------------------------------------------------------------
// Attention pass B v3: out[c,j] = bf16( sum_i V'[c,i]*exp(S[i,j]) + feat[c,j] )
// V' pre-scaled by 1/Z[i]. D[c][j] orientation (coalesced NCHW stores).
// 128 c x 64 j per block; double-buffered PT -> ONE barrier per i-chunk.
// Per iter per wave: 4 S-MFMA + 16 exp + 16 PV-MFMA. grid (2, 64, 4).
// ---------------------------------------------------------------------------
__global__ __launch_bounds__(256) void attn3_k(const bf16_t* __restrict__ QKT,
                                               const bf16_t* __restrict__ V,
                                               const float* __restrict__ rgb_feat,
                                               const float* __restrict__ chm_feat,
                                               bf16_t* __restrict__ CAT) {
    __shared__ bf16_t PT[2][64][72];  // [buf][j_local][i_local]
    const int t = threadIdx.x, cb = blockIdx.x, jb = blockIdx.y, z = blockIdx.z;
    const int w = t >> 6, lane = t & 63, quad = lane >> 4, l16 = lane & 15;
    const int qs = z ^ 2, n = z & 1;

    const bf16_t* Q = QKT + (size_t)qs * HW * 64;

    bf16x8 bS[4];  // K-side S fragments for this block's fixed j range
#pragma unroll
    for (int ns = 0; ns < 4; ns++)
        bS[ns] = *(const bf16x8*)(Q + (size_t)(jb * 64 + ns * 16 + l16) * 64 + 32 + quad * 8);

    f32x4 zero = {0.f, 0.f, 0.f, 0.f};
    f32x4 acc[2][4];
#pragma unroll
    for (int i = 0; i < 2; i++)
#pragma unroll
        for (int j = 0; j < 4; j++) acc[i][j] = zero;

    // wave's two c-strips: cb*128 + ct*64 + w*16 (+ l16)
    const bf16_t* Vr0 = V + ((size_t)z * 256 + cb * 128 + w * 16 + l16) * HW + quad * 8;
    const bf16_t* Vr1 = Vr0 + (size_t)64 * HW;

    for (int it = 0; it < 64; it++) {
        const int p = it & 1;
        // issue independent global loads early
        bf16x8 aS = *(const bf16x8*)(Q + (size_t)(it * 64 + w * 16 + l16) * 64 + quad * 8);
        bf16x8 aV[2][2];
        aV[0][0] = *(const bf16x8*)(Vr0 + it * 64);
        aV[0][1] = *(const bf16x8*)(Vr0 + it * 64 + 32);
        aV[1][0] = *(const bf16x8*)(Vr1 + it * 64);
        aV[1][1] = *(const bf16x8*)(Vr1 + it * 64 + 32);

        // S tile + exp -> PT[p]  (writes to PT[p] race-free: readers of
        // PT[p] from iter it-2 passed barrier(it-1))
#pragma unroll
        for (int ns = 0; ns < 4; ns++) {
            f32x4 s = mfma_bf16(aS, bS[ns], zero);
            union { bf16_t h[4]; unsigned long long u; } pk;
#pragma unroll
            for (int rr = 0; rr < 4; rr++) pk.h[rr] = (bf16_t)__expf(s[rr]);
            *(unsigned long long*)&PT[p][ns * 16 + l16][w * 16 + quad * 4] = pk.u;
        }
        __syncthreads();  // PT[p] ready

#pragma unroll
        for (int ns = 0; ns < 4; ns++) {
            bf16x8 b0 = *(const bf16x8*)&PT[p][ns * 16 + l16][quad * 8];
            bf16x8 b1 = *(const bf16x8*)&PT[p][ns * 16 + l16][32 + quad * 8];
#pragma unroll
            for (int ct = 0; ct < 2; ct++) {
                acc[ct][ns] = mfma_bf16(aV[ct][0], b0, acc[ct][ns]);
                acc[ct][ns] = mfma_bf16(aV[ct][1], b1, acc[ct][ns]);
            }
        }
    }

    const float* feat = ((z < 2) ? rgb_feat : chm_feat) + (size_t)n * 256 * HW;
    bf16_t* outp = CAT + (size_t)n * 512 * HW + (size_t)(z < 2 ? 0 : 256) * HW;
#pragma unroll
    for (int ct = 0; ct < 2; ct++) {
#pragma unroll
        for (int ns = 0; ns < 4; ns++) {
#pragma unroll
            for (int rr = 0; rr < 4; rr++) {
                int c = cb * 128 + ct * 64 + w * 16 + quad * 4 + rr;
                int col = jb * 64 + ns * 16 + l16;
                float v = acc[ct][ns][rr] + feat[(size_t)c * HW + col];
                outp[(size_t)c * HW + col] = (bf16_t)v;
            }
        }
    }
}

// ---------------------------------------------------------------------------
extern "C" void kernel_launch(void* const* d_in, const int* in_sizes, int n_in,
                              void* d_out, int out_size, void* d_ws, size_t ws_size,
                              hipStream_t stream) {
    (void)in_sizes; (void)n_in; (void)out_size; (void)ws_size;

    const float* rgb_feat  = (const float*)d_in[0];
    const float* chm_feat  = (const float*)d_in[1];
    const float* rgb_q_w   = (const float*)d_in[2];
    const float* rgb_q_b   = (const float*)d_in[3];
    const float* rgb_k_w   = (const float*)d_in[4];
    const float* rgb_k_b   = (const float*)d_in[5];
    const float* rgb_v_w   = (const float*)d_in[6];
    const float* rgb_v_b   = (const float*)d_in[7];
    const float* depth_q_w = (const float*)d_in[8];
    const float* depth_q_b = (const float*)d_in[9];
    const float* depth_k_w = (const float*)d_in[10];
    const float* depth_k_b = (const float*)d_in[11];
    const float* depth_v_w = (const float*)d_in[12];
    const float* depth_v_b = (const float*)d_in[13];
    const float* gate_w    = (const float*)d_in[14];
    const float* gate_b    = (const float*)d_in[15];
    const float* fus1_w    = (const float*)d_in[16];
    const float* fus1_b    = (const float*)d_in[17];
    const float* fus2_w    = (const float*)d_in[18];
    const float* fus2_b    = (const float*)d_in[19];
    const float* fus3_w    = (const float*)d_in[20];
    const float* fus3_b    = (const float*)d_in[21];
    const float* skip_w    = (const float*)d_in[22];
    const float* skip_b    = (const float*)d_in[23];

    char* ws = (char*)d_ws;
    size_t off = 0;
    auto alloc = [&](size_t bytes) -> char* {
        char* p = ws + off;
        off += (bytes + 255) & ~(size_t)255;
        return p;
    };

    bf16_t* WQK_R = (bf16_t*)alloc(64 * 256 * 2);
    bf16_t* WQK_D = (bf16_t*)alloc(64 * 256 * 2);
    bf16_t* WV_R  = (bf16_t*)alloc(256 * 256 * 2);
    bf16_t* WV_D  = (bf16_t*)alloc(256 * 256 * 2);
    bf16_t* WGATE = (bf16_t*)alloc(256 * 512 * 2);
    bf16_t* WFUS1 = (bf16_t*)alloc(512 * 512 * 2);
    bf16_t* WFUS2 = (bf16_t*)alloc(512 * 4608 * 2);
    bf16_t* WCAT  = (bf16_t*)alloc(256 * 1024 * 2);      // [skip_w | fus3_w]
    float*  BQK_R = (float*)alloc(64 * 4);
    float*  BQK_D = (float*)alloc(64 * 4);
    float*  BSUM  = (float*)alloc(256 * 4);
    bf16_t* XB    = (bf16_t*)alloc((size_t)4 * 256 * HW * 2);    // [XR n0,n1; XC n0,n1]
    bf16_t* QKT   = (bf16_t*)alloc((size_t)4 * HW * 64 * 2);     // [z][pixel][64]
    float*  ZBUF  = (float*)alloc((size_t)4 * HW * 4);           // [k][HW]
    bf16_t* V4    = (bf16_t*)alloc((size_t)4 * 256 * HW * 2);    // CHW [z][c][pixel]
    bf16_t* CAT   = (bf16_t*)alloc((size_t)NB * 512 * HW * 2);
    bf16_t* FY    = (bf16_t*)alloc((size_t)NB * 1024 * HW * 2);  // [F ; Y2]
    bf16_t* Y1    = (bf16_t*)alloc((size_t)NB * 512 * HW * 2);

    bf16_t* XR = XB;
    bf16_t* XC = XB + (size_t)2 * 256 * HW;

    // ---- prep: batched convert + bias pack ---------------------------------
    CvtJobs J;
    int cum = 0, nj = 0;
    auto addjob = [&](const float* s, bf16_t* d, int cnt, int rl, int rs, int ro) {
        J.src[nj] = s; J.dst[nj] = d; cum += cnt / 8; J.vend[nj] = cum;
        J.rowlen[nj] = rl; J.rowstride[nj] = rs; J.rowoff[nj] = ro; nj++;
    };
    addjob(rgb_feat, XR, NB * 256 * HW, 0, 0, 0);
    addjob(chm_feat, XC, NB * 256 * HW, 0, 0, 0);
    addjob(rgb_q_w, WQK_R, 32 * 256, 0, 0, 0);
    addjob(rgb_k_w, WQK_R + 32 * 256, 32 * 256, 0, 0, 0);
    addjob(depth_q_w, WQK_D, 32 * 256, 0, 0, 0);
    addjob(depth_k_w, WQK_D + 32 * 256, 32 * 256, 0, 0, 0);
    addjob(rgb_v_w, WV_R, 256 * 256, 0, 0, 0);
    addjob(depth_v_w, WV_D, 256 * 256, 0, 0, 0);
    addjob(gate_w, WGATE, 256 * 512, 0, 0, 0);
    addjob(fus1_w, WFUS1, 512 * 512, 0, 0, 0);
    addjob(skip_w, WCAT, 256 * 512, 512, 1024, 0);
    addjob(fus3_w, WCAT, 256 * 512, 512, 1024, 512);
    int totalvec = cum;
    convert_batch_k<<<dim3((totalvec + 255) / 256), 256, 0, stream>>>(J, totalvec);
    reorder_fus2_k<<<dim3(512 * 4608 / 256), 256, 0, stream>>>(fus2_w, WFUS2);
    pack_bias_k<<<dim3(1), 256, 0, stream>>>(rgb_q_b, rgb_k_b, depth_q_b, depth_k_b,
                                             skip_b, fus3_b, BQK_R, BQK_D, BSUM);

    // ---- q/k projections -> QKT[z][pixel][64] (z: 0,1 rgb; 2,3 depth) ------
    gemm_k<6, true><<<dim3(1, 64, 4), 256, 0, stream>>>(
        WQK_R, WQK_D, XB, BQK_R, BQK_D, QKT, nullptr, 64, 256, (size_t)256 * HW, 0);

    // ---- attention pass A: softmax denominators ----------------------------
    rowsum_k<<<dim3(128, 4), 256, 0, stream>>>(QKT, ZBUF);

    // ---- v projections, folded 1/Z scale -> V4 CHW -------------------------
    gemm_k<3, true><<<dim3(4, 64, 4), 256, 0, stream>>>(
        WV_R, WV_D, XB, rgb_v_b, depth_v_b, V4, ZBUF, 256, 256, (size_t)256 * HW, (size_t)256 * HW);

    // ---- attention pass B + residual -> CAT=[br;bd] NCHW -------------------
    attn3_k<<<dim3(2, 64, 4), 256, 0, stream>>>(QKT, V4, rgb_feat, chm_feat, CAT);

    // ---- gate + gated fusion fused epilogue -> FY rows 0..511 --------------
    gemm_k<5, true><<<dim3(4, 64, NB), 256, 0, stream>>>(
        WGATE, WGATE, CAT, gate_b, gate_b, FY, CAT, 256, 512, (size_t)512 * HW, 0);

    // ---- fus1 (relu) -------------------------------------------------------
    gemm_k<1, true><<<dim3(8, 64, NB), 256, 0, stream>>>(
        WFUS1, WFUS1, FY, fus1_b, fus1_b, Y1, nullptr, 512, 512, (size_t)1024 * HW, (size_t)512 * HW);

    // ---- fus2 conv3x3 (relu) -> FY rows 512..1023 --------------------------
    conv3_k<<<dim3(4, 64, NB), 256, 0, stream>>>(WFUS2, Y1, fus2_b,
                                                 FY + (size_t)512 * HW, (size_t)1024 * HW);

    // ---- merged skip+fus3: d_out = [skip_w|fus3_w] . [F;Y2] + (skip_b+fus3_b)
    gemm_k<0, false><<<dim3(4, 64, NB), 256, 0, stream>>>(
        WCAT, WCAT, FY, BSUM, BSUM, d_out, nullptr, 256, 1024, (size_t)1024 * HW, (size_t)256 * HW);
}

// Round 7
// 389.002 us; speedup vs baseline: 1.3680x; 1.0339x over previous
//
#include <hip/hip_runtime.h>
#include <stdint.h>

// ---------------------------------------------------------------------------
// GC_FFM fusion block on MI355X (gfx950), bf16 MFMA pipeline.
// N=2, C=256, RC=32, H=W=64, HW=4096.
// R7: R6 + fus1 outputs Y1 in NHWC (transposed-pack epilogue) so conv3's
//     LDS staging is a straight vectorized copy (no transpose scatter, no
//     bank conflicts, 7 b128 writes/thread/chunk instead of 48 b16).
// R5 lesson: LDS-free GEMMs with large-stride operands = latency-bound.
// R6 lesson: conv3 staging transpose (scalar b16 scatter) = conflict+VALU wall.
// ---------------------------------------------------------------------------

typedef __bf16 bf16_t;
typedef __bf16 bf16x8 __attribute__((ext_vector_type(8)));
typedef float f32x4 __attribute__((ext_vector_type(4)));

#define HW 4096
#define NB 2

__device__ inline f32x4 mfma_bf16(bf16x8 a, bf16x8 b, f32x4 c) {
    return __builtin_amdgcn_mfma_f32_16x16x32_bf16(a, b, c, 0, 0, 0);
}

// ---------------------------------------------------------------------------
// Batched fp32 -> bf16 conversion (one launch for all weights + features).
// ---------------------------------------------------------------------------
#define MAXJOB 12
struct CvtJobs {
    const float* src[MAXJOB];
    bf16_t* dst[MAXJOB];
    int vend[MAXJOB];     // cumulative end, vec8 units
    int rowlen[MAXJOB];
    int rowstride[MAXJOB];
    int rowoff[MAXJOB];
};

__global__ __launch_bounds__(256) void convert_batch_k(CvtJobs J, int totalvec) {
    int gv = blockIdx.x * 256 + threadIdx.x;
    if (gv >= totalvec) return;
    int j = 0;
    while (gv >= J.vend[j]) j++;
    int vbase = (j == 0) ? 0 : J.vend[j - 1];
    int e = (gv - vbase) * 8;
    const float* s = J.src[j] + e;
    float4 f0 = *(const float4*)s;
    float4 f1 = *(const float4*)(s + 4);
    bf16x8 o;
    o[0] = (bf16_t)f0.x; o[1] = (bf16_t)f0.y; o[2] = (bf16_t)f0.z; o[3] = (bf16_t)f0.w;
    o[4] = (bf16_t)f1.x; o[5] = (bf16_t)f1.y; o[6] = (bf16_t)f1.z; o[7] = (bf16_t)f1.w;
    int di = e;
    if (J.rowlen[j])
        di = (e / J.rowlen[j]) * J.rowstride[j] + J.rowoff[j] + (e % J.rowlen[j]);
    *(bf16x8*)(J.dst[j] + di) = o;
}

// pack q/k biases into stacked [64] buffers + combined skip/fus3 bias
__global__ __launch_bounds__(256) void pack_bias_k(const float* qr, const float* kr,
                                                   const float* qd, const float* kd,
                                                   const float* sb, const float* fb,
                                                   float* BQK_R, float* BQK_D, float* BSUM) {
    int t = threadIdx.x;
    if (t < 32) {
        BQK_R[t] = qr[t]; BQK_R[32 + t] = kr[t];
        BQK_D[t] = qd[t]; BQK_D[32 + t] = kd[t];
    }
    BSUM[t] = sb[t] + fb[t];
}

// fus2_w [O=512][C=512][3][3] -> A'[o][ (dy*3+dx)*512 + c ]
__global__ __launch_bounds__(256) void reorder_fus2_k(const float* __restrict__ src,
                                                      bf16_t* __restrict__ dst) {
    int idx = blockIdx.x * 256 + threadIdx.x;
    if (idx >= 512 * 4608) return;
    int o = idx / 4608;
    int t = idx % 4608;
    int t9 = t / 512;
    int c  = t % 512;
    dst[idx] = (bf16_t)src[(size_t)o * 4608 + c * 9 + t9];
}

// ---------------------------------------------------------------------------
// Generic bf16 GEMM (R4-proven): out = epi( A[z] . B[z] + bias ), dual-A.
// EPI: 0 none->fp32, 1 relu->bf16, 3 col-div by aux, 5 gate-fuse,
//      6 QKT transposed store, 7 NHWC transposed relu store (Y1)
// ---------------------------------------------------------------------------
template <int EPI, bool OUT_BF16>
__global__ __launch_bounds__(256) void gemm_k(const bf16_t* __restrict__ A,
                                              const bf16_t* __restrict__ A2,
                                              const bf16_t* __restrict__ B,
                                              const float* __restrict__ bias,
                                              const float* __restrict__ bias2,
                                              void* __restrict__ outp,
                                              const void* __restrict__ aux,
                                              int M, int K, size_t strideB, size_t strideO) {
    __shared__ bf16_t Bt[64][72];
    const int t = threadIdx.x;
    const int mb = blockIdx.x, jb = blockIdx.y, n = blockIdx.z;
    const int w = t >> 6, lane = t & 63, quad = lane >> 4, l16 = lane & 15;

    const bf16_t* Au = (n >= 2) ? A2 : A;
    const float* biasu = (n >= 2) ? bias2 : bias;

    const bf16_t* Bb = B + (size_t)n * strideB + jb * 64;
    const int srow = t >> 2;
    const int scol = (t & 3) << 4;

    f32x4 zero = {0.f, 0.f, 0.f, 0.f};
    f32x4 acc[4] = {zero, zero, zero, zero};

    const bf16_t* Arow = Au + (size_t)(mb * 64 + w * 16 + l16) * K + quad * 8;

    for (int k0 = 0; k0 < K; k0 += 64) {
        const bf16_t* src = Bb + (size_t)(k0 + srow) * HW + scol;
        bf16x8 v0 = *(const bf16x8*)src;
        bf16x8 v1 = *(const bf16x8*)(src + 8);
        __syncthreads();
#pragma unroll
        for (int e = 0; e < 8; e++) Bt[scol + e][srow] = v0[e];
#pragma unroll
        for (int e = 0; e < 8; e++) Bt[scol + 8 + e][srow] = v1[e];
        __syncthreads();

        bf16x8 a0 = *(const bf16x8*)(Arow + k0);
        bf16x8 a1 = *(const bf16x8*)(Arow + k0 + 32);
#pragma unroll
        for (int ns = 0; ns < 4; ns++) {
            bf16x8 b0 = *(const bf16x8*)&Bt[ns * 16 + l16][quad * 8];
            bf16x8 b1 = *(const bf16x8*)&Bt[ns * 16 + l16][32 + quad * 8];
            acc[ns] = mfma_bf16(a0, b0, acc[ns]);
            acc[ns] = mfma_bf16(a1, b1, acc[ns]);
        }
    }

    if (EPI == 6) {
        // transposed store: QKT[z][col][64] (M=64, mb=0)
#pragma unroll
        for (int ns = 0; ns < 4; ns++) {
            int col = jb * 64 + ns * 16 + l16;
            union { bf16_t h[4]; unsigned long long u; } pk;
#pragma unroll
            for (int rr = 0; rr < 4; rr++) {
                int m = w * 16 + quad * 4 + rr;
                pk.h[rr] = (bf16_t)(acc[ns][rr] + biasu[m]);
            }
            *(unsigned long long*)((bf16_t*)outp +
                ((size_t)n * HW + col) * 64 + w * 16 + quad * 4) = pk.u;
        }
    } else if (EPI == 7) {
        // NHWC transposed relu store: Y1[(n*HW + col)*512 + m_base..+4]
        const int m_base = mb * 64 + w * 16 + quad * 4;
#pragma unroll
        for (int ns = 0; ns < 4; ns++) {
            int col = jb * 64 + ns * 16 + l16;
            union { bf16_t h[4]; unsigned long long u; } pk;
#pragma unroll
            for (int rr = 0; rr < 4; rr++) {
                float v = acc[ns][rr] + biasu[m_base + rr];
                pk.h[rr] = (bf16_t)(v > 0.f ? v : 0.f);
            }
            *(unsigned long long*)((bf16_t*)outp +
                ((size_t)n * HW + col) * 512 + m_base) = pk.u;
        }
    } else if (EPI == 5) {
        const bf16_t* catp = (const bf16_t*)aux;
        bf16_t* f = (bf16_t*)outp;
#pragma unroll
        for (int ns = 0; ns < 4; ns++) {
#pragma unroll
            for (int rr = 0; rr < 4; rr++) {
                int m = mb * 64 + w * 16 + quad * 4 + rr;
                int col = jb * 64 + ns * 16 + l16;
                float v = acc[ns][rr] + biasu[m];
                float g = 1.f / (1.f + __expf(-v));
                size_t base = (size_t)n * 512 * HW + (size_t)m * HW + col;
                float br = (float)catp[base];
                float bd = (float)catp[base + (size_t)256 * HW];
                size_t ob = (size_t)n * 1024 * HW + (size_t)m * HW + col;
                f[ob] = (bf16_t)(br * g + bd * (1.f - g));
                f[ob + (size_t)256 * HW] = (bf16_t)(br * bd);
            }
        }
    } else {
#pragma unroll
        for (int ns = 0; ns < 4; ns++) {
#pragma unroll
            for (int rr = 0; rr < 4; rr++) {
                int m = mb * 64 + w * 16 + quad * 4 + rr;
                int col = jb * 64 + ns * 16 + l16;
                float v = acc[ns][rr] + biasu[m];
                if (EPI == 1) v = v > 0.f ? v : 0.f;
                else if (EPI == 3) v = v / ((const float*)aux)[n * HW + col];
                size_t oi = (size_t)n * strideO + (size_t)m * HW + col;
                if (OUT_BF16) ((bf16_t*)outp)[oi] = (bf16_t)v;
                else ((float*)outp)[oi] = v;
            }
        }
    }
}

// ---------------------------------------------------------------------------
// conv3x3 implicit GEMM v2: NHWC input (Y1 [n][pix][512]) -> vectorized,
// transpose-free, conflict-free LDS staging. Tile kTn[px_slot][ch]:
// px_slot = r*66 + (x+1), r in 0..2 (rows y-1..y+1), 64 ch per chunk.
// Block 128 m x 64 px (one y row), 4 waves (wave = 32 m). 9 taps read
// shifted b-frags from the staged tile. Output NCHW rows (coalesced).
// ---------------------------------------------------------------------------
__global__ __launch_bounds__(256) void conv3_k(const bf16_t* __restrict__ A,
                                               const bf16_t* __restrict__ Y1n,
                                               const float* __restrict__ bias,
                                               bf16_t* __restrict__ outp,
                                               size_t strideN) {
    __shared__ bf16_t kTn[198][72];  // [px_slot][channel], pad 72 (144B rows)
    const int t = threadIdx.x;
    const int mb = blockIdx.x, y = blockIdx.y, n = blockIdx.z;
    const int w = t >> 6, lane = t & 63, quad = lane >> 4, l16 = lane & 15;

    f32x4 zero = {0.f, 0.f, 0.f, 0.f};
    f32x4 acc[2][4];
#pragma unroll
    for (int i = 0; i < 2; i++)
#pragma unroll
        for (int j = 0; j < 4; j++) acc[i][j] = zero;

    const bf16_t* Yb = Y1n + (size_t)n * HW * 512;

    const bf16_t* Arow0 = A + (size_t)(mb * 128 + w * 32 + l16) * 4608 + quad * 8;
    const bf16_t* Arow1 = Arow0 + (size_t)16 * 4608;

    // staging slot geometry: 198 px_slots x 8 ch-segments = 1584 16B units
    int pxs[7], seg[7], gidx[7];
    bool ok[7], act[7];
#pragma unroll
    for (int i = 0; i < 7; i++) {
        int slot = t + i * 256;
        act[i] = slot < 1584;
        int ps = act[i] ? (slot >> 3) : 0;
        pxs[i] = ps;
        seg[i] = slot & 7;
        int r = ps / 66, xm = ps % 66;
        int yy = y + r - 1, xx = xm - 1;
        ok[i] = act[i] && ((unsigned)yy < 64u) && ((unsigned)xx < 64u);
        gidx[i] = ok[i] ? (yy * 64 + xx) : 0;
    }

    for (int c0 = 0; c0 < 512; c0 += 64) {
        bf16x8 vals[7];
#pragma unroll
        for (int i = 0; i < 7; i++) {
            bf16x8 v;
            if (ok[i]) {
                v = *(const bf16x8*)(Yb + (size_t)gidx[i] * 512 + c0 + seg[i] * 8);
            } else {
#pragma unroll
                for (int e = 0; e < 8; e++) v[e] = (bf16_t)0.f;
            }
            vals[i] = v;
        }
        __syncthreads();  // previous chunk's readers done
#pragma unroll
        for (int i = 0; i < 7; i++)
            if (act[i]) *(bf16x8*)&kTn[pxs[i]][seg[i] * 8] = vals[i];
        __syncthreads();  // tile ready

#pragma unroll
        for (int t9 = 0; t9 < 9; t9++) {
            const int dy = t9 / 3, dx = t9 % 3;
            const bf16_t* ap0 = Arow0 + t9 * 512 + c0;
            const bf16_t* ap1 = Arow1 + t9 * 512 + c0;
            bf16x8 a00 = *(const bf16x8*)(ap0);
            bf16x8 a01 = *(const bf16x8*)(ap0 + 32);
            bf16x8 a10 = *(const bf16x8*)(ap1);
            bf16x8 a11 = *(const bf16x8*)(ap1 + 32);
#pragma unroll
            for (int ns = 0; ns < 4; ns++) {
                int p = dy * 66 + ns * 16 + l16 + dx;
                bf16x8 b0 = *(const bf16x8*)&kTn[p][quad * 8];
                bf16x8 b1 = *(const bf16x8*)&kTn[p][32 + quad * 8];
                acc[0][ns] = mfma_bf16(a00, b0, acc[0][ns]);
                acc[0][ns] = mfma_bf16(a01, b1, acc[0][ns]);
                acc[1][ns] = mfma_bf16(a10, b0, acc[1][ns]);
                acc[1][ns] = mfma_bf16(a11, b1, acc[1][ns]);
            }
        }
    }

#pragma unroll
    for (int ms = 0; ms < 2; ms++) {
#pragma unroll
        for (int ns = 0; ns < 4; ns++) {
#pragma unroll
            for (int rr = 0; rr < 4; rr++) {
                int m = mb * 128 + w * 32 + ms * 16 + quad * 4 + rr;
                int x = ns * 16 + l16;
                float v = acc[ms][ns][rr] + bias[m];
                v = v > 0.f ? v : 0.f;
                outp[(size_t)n * strideN + (size_t)m * HW + y * 64 + x] = (bf16_t)v;
            }
        }
    }
}

// ---------------------------------------------------------------------------
// Attention pass A v2 (R6-proven): Z[k][i] = sum_j exp(S[i,j]).
// ---------------------------------------------------------------------------
__global__ __launch_bounds__(256) void rowsum_k(const bf16_t* __restrict__ QKT,
                                                float* __restrict__ Z) {
    __shared__ float Zp[2][32];
    const int t = threadIdx.x, ib = blockIdx.x, k = blockIdx.y;
    const int w = t >> 6, lane = t & 63, quad = lane >> 4, l16 = lane & 15;
    const int is = w & 1, jh = w >> 1;
    const int qs = k ^ 2;
    const bf16_t* Q = QKT + (size_t)qs * HW * 64;

    bf16x8 a = *(const bf16x8*)(Q + (size_t)(ib * 32 + is * 16 + l16) * 64 + quad * 8);
    float zacc[4] = {0.f, 0.f, 0.f, 0.f};
    f32x4 zero = {0.f, 0.f, 0.f, 0.f};

    for (int jt = jh * 32; jt < jh * 32 + 32; jt++) {
#pragma unroll
        for (int ns = 0; ns < 4; ns++) {
            bf16x8 b = *(const bf16x8*)(Q + (size_t)(jt * 64 + ns * 16 + l16) * 64 + 32 + quad * 8);
            f32x4 s = mfma_bf16(a, b, zero);
#pragma unroll
            for (int rr = 0; rr < 4; rr++) zacc[rr] += __expf(s[rr]);
        }
    }

#pragma unroll
    for (int rr = 0; rr < 4; rr++) {
        for (int mask = 1; mask < 16; mask <<= 1)
            zacc[rr] += __shfl_xor(zacc[rr], mask, 64);
    }
    if (l16 == 0) {
#pragma unroll
        for (int rr = 0; rr < 4; rr++)
            Zp[jh][is * 16 + quad * 4 + rr] = zacc[rr];
    }
    __syncthreads();
    if (t < 32)
        Z[(size_t)k * HW + ib * 32 + t] = Zp[0][t] + Zp[1][t];
}

// ---------------------------------------------------------------------------
// Attention pass B v3 (R6-proven): out[c,j] = sum_i V'[c,i]*exp(S[i,j]) + feat.
// ---------------------------------------------------------------------------
__global__ __launch_bounds__(256) void attn3_k(const bf16_t* __restrict__ QKT,
                                               const bf16_t* __restrict__ V,
                                               const float* __restrict__ rgb_feat,
                                               const float* __restrict__ chm_feat,
                                               bf16_t* __restrict__ CAT) {
    __shared__ bf16_t PT[2][64][72];  // [buf][j_local][i_local]
    const int t = threadIdx.x, cb = blockIdx.x, jb = blockIdx.y, z = blockIdx.z;
    const int w = t >> 6, lane = t & 63, quad = lane >> 4, l16 = lane & 15;
    const int qs = z ^ 2, n = z & 1;

    const bf16_t* Q = QKT + (size_t)qs * HW * 64;

    bf16x8 bS[4];
#pragma unroll
    for (int ns = 0; ns < 4; ns++)
        bS[ns] = *(const bf16x8*)(Q + (size_t)(jb * 64 + ns * 16 + l16) * 64 + 32 + quad * 8);

    f32x4 zero = {0.f, 0.f, 0.f, 0.f};
    f32x4 acc[2][4];
#pragma unroll
    for (int i = 0; i < 2; i++)
#pragma unroll
        for (int j = 0; j < 4; j++) acc[i][j] = zero;

    const bf16_t* Vr0 = V + ((size_t)z * 256 + cb * 128 + w * 16 + l16) * HW + quad * 8;
    const bf16_t* Vr1 = Vr0 + (size_t)64 * HW;

    for (int it = 0; it < 64; it++) {
        const int p = it & 1;
        bf16x8 aS = *(const bf16x8*)(Q + (size_t)(it * 64 + w * 16 + l16) * 64 + quad * 8);
        bf16x8 aV[2][2];
        aV[0][0] = *(const bf16x8*)(Vr0 + it * 64);
        aV[0][1] = *(const bf16x8*)(Vr0 + it * 64 + 32);
        aV[1][0] = *(const bf16x8*)(Vr1 + it * 64);
        aV[1][1] = *(const bf16x8*)(Vr1 + it * 64 + 32);

#pragma unroll
        for (int ns = 0; ns < 4; ns++) {
            f32x4 s = mfma_bf16(aS, bS[ns], zero);
            union { bf16_t h[4]; unsigned long long u; } pk;
#pragma unroll
            for (int rr = 0; rr < 4; rr++) pk.h[rr] = (bf16_t)__expf(s[rr]);
            *(unsigned long long*)&PT[p][ns * 16 + l16][w * 16 + quad * 4] = pk.u;
        }
        __syncthreads();  // PT[p] ready

#pragma unroll
        for (int ns = 0; ns < 4; ns++) {
            bf16x8 b0 = *(const bf16x8*)&PT[p][ns * 16 + l16][quad * 8];
            bf16x8 b1 = *(const bf16x8*)&PT[p][ns * 16 + l16][32 + quad * 8];
#pragma unroll
            for (int ct = 0; ct < 2; ct++) {
                acc[ct][ns] = mfma_bf16(aV[ct][0], b0, acc[ct][ns]);
                acc[ct][ns] = mfma_bf16(aV[ct][1], b1, acc[ct][ns]);
            }
        }
    }

    const float* feat = ((z < 2) ? rgb_feat : chm_feat) + (size_t)n * 256 * HW;
    bf16_t* outp = CAT + (size_t)n * 512 * HW + (size_t)(z < 2 ? 0 : 256) * HW;
#pragma unroll
    for (int ct = 0; ct < 2; ct++) {
#pragma unroll
        for (int ns = 0; ns < 4; ns++) {
#pragma unroll
            for (int rr = 0; rr < 4; rr++) {
                int c = cb * 128 + ct * 64 + w * 16 + quad * 4 + rr;
                int col = jb * 64 + ns * 16 + l16;
                float v = acc[ct][ns][rr] + feat[(size_t)c * HW + col];
                outp[(size_t)c * HW + col] = (bf16_t)v;
            }
        }
    }
}

// ---------------------------------------------------------------------------
extern "C" void kernel_launch(void* const* d_in, const int* in_sizes, int n_in,
                              void* d_out, int out_size, void* d_ws, size_t ws_size,
                              hipStream_t stream) {
    (void)in_sizes; (void)n_in; (void)out_size; (void)ws_size;

    const float* rgb_feat  = (const float*)d_in[0];
    const float* chm_feat  = (const float*)d_in[1];
    const float* rgb_q_w   = (const float*)d_in[2];
    const float* rgb_q_b   = (const float*)d_in[3];
    const float* rgb_k_w   = (const float*)d_in[4];
    const float* rgb_k_b   = (const float*)d_in[5];
    const float* rgb_v_w   = (const float*)d_in[6];
    const float* rgb_v_b   = (const float*)d_in[7];
    const float* depth_q_w = (const float*)d_in[8];
    const float* depth_q_b = (const float*)d_in[9];
    const float* depth_k_w = (const float*)d_in[10];
    const float* depth_k_b = (const float*)d_in[11];
    const float* depth_v_w = (const float*)d_in[12];
    const float* depth_v_b = (const float*)d_in[13];
    const float* gate_w    = (const float*)d_in[14];
    const float* gate_b    = (const float*)d_in[15];
    const float* fus1_w    = (const float*)d_in[16];
    const float* fus1_b    = (const float*)d_in[17];
    const float* fus2_w    = (const float*)d_in[18];
    const float* fus2_b    = (const float*)d_in[19];
    const float* fus3_w    = (const float*)d_in[20];
    const float* fus3_b    = (const float*)d_in[21];
    const float* skip_w    = (const float*)d_in[22];
    const float* skip_b    = (const float*)d_in[23];

    char* ws = (char*)d_ws;
    size_t off = 0;
    auto alloc = [&](size_t bytes) -> char* {
        char* p = ws + off;
        off += (bytes + 255) & ~(size_t)255;
        return p;
    };

    bf16_t* WQK_R = (bf16_t*)alloc(64 * 256 * 2);
    bf16_t* WQK_D = (bf16_t*)alloc(64 * 256 * 2);
    bf16_t* WV_R  = (bf16_t*)alloc(256 * 256 * 2);
    bf16_t* WV_D  = (bf16_t*)alloc(256 * 256 * 2);
    bf16_t* WGATE = (bf16_t*)alloc(256 * 512 * 2);
    bf16_t* WFUS1 = (bf16_t*)alloc(512 * 512 * 2);
    bf16_t* WFUS2 = (bf16_t*)alloc(512 * 4608 * 2);
    bf16_t* WCAT  = (bf16_t*)alloc(256 * 1024 * 2);      // [skip_w | fus3_w]
    float*  BQK_R = (float*)alloc(64 * 4);
    float*  BQK_D = (float*)alloc(64 * 4);
    float*  BSUM  = (float*)alloc(256 * 4);
    bf16_t* XB    = (bf16_t*)alloc((size_t)4 * 256 * HW * 2);    // [XR n0,n1; XC n0,n1]
    bf16_t* QKT   = (bf16_t*)alloc((size_t)4 * HW * 64 * 2);     // [z][pixel][64]
    float*  ZBUF  = (float*)alloc((size_t)4 * HW * 4);           // [k][HW]
    bf16_t* V4    = (bf16_t*)alloc((size_t)4 * 256 * HW * 2);    // CHW [z][c][pixel]
    bf16_t* CAT   = (bf16_t*)alloc((size_t)NB * 512 * HW * 2);
    bf16_t* FY    = (bf16_t*)alloc((size_t)NB * 1024 * HW * 2);  // [F ; Y2] NCHW
    bf16_t* Y1    = (bf16_t*)alloc((size_t)NB * HW * 512 * 2);   // NHWC [n][pix][512]

    bf16_t* XR = XB;
    bf16_t* XC = XB + (size_t)2 * 256 * HW;

    // ---- prep: batched convert + bias pack ---------------------------------
    CvtJobs J;
    int cum = 0, nj = 0;
    auto addjob = [&](const float* s, bf16_t* d, int cnt, int rl, int rs, int ro) {
        J.src[nj] = s; J.dst[nj] = d; cum += cnt / 8; J.vend[nj] = cum;
        J.rowlen[nj] = rl; J.rowstride[nj] = rs; J.rowoff[nj] = ro; nj++;
    };
    addjob(rgb_feat, XR, NB * 256 * HW, 0, 0, 0);
    addjob(chm_feat, XC, NB * 256 * HW, 0, 0, 0);
    addjob(rgb_q_w, WQK_R, 32 * 256, 0, 0, 0);
    addjob(rgb_k_w, WQK_R + 32 * 256, 32 * 256, 0, 0, 0);
    addjob(depth_q_w, WQK_D, 32 * 256, 0, 0, 0);
    addjob(depth_k_w, WQK_D + 32 * 256, 32 * 256, 0, 0, 0);
    addjob(rgb_v_w, WV_R, 256 * 256, 0, 0, 0);
    addjob(depth_v_w, WV_D, 256 * 256, 0, 0, 0);
    addjob(gate_w, WGATE, 256 * 512, 0, 0, 0);
    addjob(fus1_w, WFUS1, 512 * 512, 0, 0, 0);
    addjob(skip_w, WCAT, 256 * 512, 512, 1024, 0);
    addjob(fus3_w, WCAT, 256 * 512, 512, 1024, 512);
    int totalvec = cum;
    convert_batch_k<<<dim3((totalvec + 255) / 256), 256, 0, stream>>>(J, totalvec);
    reorder_fus2_k<<<dim3(512 * 4608 / 256), 256, 0, stream>>>(fus2_w, WFUS2);
    pack_bias_k<<<dim3(1), 256, 0, stream>>>(rgb_q_b, rgb_k_b, depth_q_b, depth_k_b,
                                             skip_b, fus3_b, BQK_R, BQK_D, BSUM);

    // ---- q/k projections -> QKT[z][pixel][64] (z: 0,1 rgb; 2,3 depth) ------
    gemm_k<6, true><<<dim3(1, 64, 4), 256, 0, stream>>>(
        WQK_R, WQK_D, XB, BQK_R, BQK_D, QKT, nullptr, 64, 256, (size_t)256 * HW, 0);

    // ---- attention pass A: softmax denominators ----------------------------
    rowsum_k<<<dim3(128, 4), 256, 0, stream>>>(QKT, ZBUF);

    // ---- v projections, folded 1/Z scale -> V4 CHW -------------------------
    gemm_k<3, true><<<dim3(4, 64, 4), 256, 0, stream>>>(
        WV_R, WV_D, XB, rgb_v_b, depth_v_b, V4, ZBUF, 256, 256, (size_t)256 * HW, (size_t)256 * HW);

    // ---- attention pass B + residual -> CAT=[br;bd] NCHW -------------------
    attn3_k<<<dim3(2, 64, 4), 256, 0, stream>>>(QKT, V4, rgb_feat, chm_feat, CAT);

    // ---- gate + gated fusion fused epilogue -> FY rows 0..511 --------------
    gemm_k<5, true><<<dim3(4, 64, NB), 256, 0, stream>>>(
        WGATE, WGATE, CAT, gate_b, gate_b, FY, CAT, 256, 512, (size_t)512 * HW, 0);

    // ---- fus1 (relu) -> Y1 NHWC --------------------------------------------
    gemm_k<7, true><<<dim3(8, 64, NB), 256, 0, stream>>>(
        WFUS1, WFUS1, FY, fus1_b, fus1_b, Y1, nullptr, 512, 512, (size_t)1024 * HW, 0);

    // ---- fus2 conv3x3 (relu) -> FY rows 512..1023 --------------------------
    conv3_k<<<dim3(4, 64, NB), 256, 0, stream>>>(WFUS2, Y1, fus2_b,
                                                 FY + (size_t)512 * HW, (size_t)1024 * HW);

    // ---- merged skip+fus3: d_out = [skip_w|fus3_w] . [F;Y2] + (skip_b+fus3_b)
    gemm_k<0, false><<<dim3(4, 64, NB), 256, 0, stream>>>(
        WCAT, WCAT, FY, BSUM, BSUM, d_out, nullptr, 256, 1024, (size_t)1024 * HW, (size_t)256 * HW);
}